// Round 12
// baseline (75.810 us; speedup 1.0000x reference)
//
#include <hip/hip_runtime.h>
#include <math.h>

typedef unsigned short u16;
typedef unsigned int u32;
typedef __attribute__((ext_vector_type(8))) short short8v;    // 8 bf16 (4 VGPR)
typedef __attribute__((ext_vector_type(4))) float f32x4;

// ---------------------------------------------------------------------------
// ws layout (f32 units):
//   x1pn [b][34][34][128] bf16 @ 0          (4,734,976 f32)
//   x0pn [b][34][34][64]  bf16 @ 4,734,976  (2,367,488 f32)
//   x2b  [kb=512][b=64][k'=256] bf16 @ 7,102,464  (4,194,304 f32)
//   partial [64brow][512kb][64n] f32 @ 0 (over dead x1pn, 2,097,152)
//   w1q2 bf16 @ 11,300,000 (73,728 u16), w2p bf16 @ 11,340,000 (36,864 u16)
// ---------------------------------------------------------------------------
#define X0PN_OFF 4734976
#define X2B_OFF  7102464
#define W1Q_OFF  11300000
#define W2P_OFF  11340000

__device__ __forceinline__ u16 f2bf(float f) {
    union { float f; u32 i; } c; c.f = f;
    u32 r = c.i + 0x7fffu + ((c.i >> 16) & 1u);   // RNE
    return (u16)(r >> 16);
}

// ---------------- prep (borders + weight packs) fused with l0 MFMA -----------
// w1q2: B-frags for l1's j-contiguous tiling. Frag idx = ((g*2+jb)*9+tap)*2+h.
// k' = 8*khi+j ; global k = 32h+k' ; r = k>>2, ci = k&3 ; A chan = 32h+k' (identity).
// col n = 64jb+4col+g ; i0 = 4*(col&3)+g ; valid iff r in S(i0), m = position.
__global__ __launch_bounds__(256) void prep_l0(const float* __restrict__ cw1,
    const float* __restrict__ cw2, const float* __restrict__ in,
    const float* __restrict__ cw0, const float* __restrict__ cb0,
    u16* __restrict__ x0pn, u16* __restrict__ x1pn,
    u16* __restrict__ w1q2, u16* __restrict__ w2p) {
    int bi = blockIdx.x;
    if (bi < 1224) {
        int t = bi * 256 + threadIdx.x;           // 313,344 total
        if (t < 202752) {
            uint4 z = {0u, 0u, 0u, 0u};
            int cell, v; u16* base; int nch;
            if (t < 67584) { v = t & 7; cell = t >> 3; base = x0pn; nch = 64; }
            else { int u = t - 67584; v = u & 15; cell = u >> 4; base = x1pn; nch = 128; }
            int b = cell / 132, ci = cell - b * 132;
            int y, x;
            if (ci < 34)       { y = 0;       x = ci; }
            else if (ci < 68)  { y = 33;      x = ci - 34; }
            else if (ci < 100) { y = ci - 67; x = 0; }
            else               { y = ci - 99; x = 33; }
            *(uint4*)(base + ((b * 34 + y) * 34 + x) * nch + v * 8) = z;
            return;
        }
        if (t < 276480) {
            int u0 = t - 202752;                  // w1q2: 73,728 elements
            int j = u0 & 7, lane = (u0 >> 3) & 63;
            int idx = u0 >> 9;                    // 0..143
            int h = idx & 1;
            int tapi = (idx >> 1) % 9;
            int gj = (idx >> 1) / 9;              // g*2+jb
            int g = gj >> 1, jb = gj & 1;
            int colB = lane & 15, khi = lane >> 4;
            int kk = 8 * khi + j;                 // k' 0..31
            int r = 8 * h + (kk >> 2);
            int ci = kk & 3;
            int n = 64 * jb + 4 * colB + g;
            int i0 = 4 * (colB & 3) + g;
            int m = -1;
            if (i0 >= 3) { if (r >= i0 - 3 && r <= i0) m = r - i0 + 3; }
            else { if (r <= i0) m = r; else if (r >= 13 + i0) m = r - 12; }
            float v = 0.f;
            if (m >= 0) v = cw1[(tapi * 16 + 4 * ci + m) * 128 + n];
            w1q2[u0] = f2bf(v);
            return;
        }
        {
            int u = t - 276480;                   // w2p: 36,864 elements
            int j = u & 7, lane = (u >> 3) & 63;
            int nt = (u >> 9) & 1;
            int gt = u >> 10, tap = gt % 9, g = gt / 9;
            int k = 8 * (lane >> 4) + j;
            int f = 4 * (k >> 2) + (k & 3);
            int n = g + 4 * (nt * 16 + (lane & 15));
            w2p[u] = f2bf(cw2[(tap * 32 + f) * 128 + n]);
        }
        return;
    }
    // ---- l0 path: MFMA im2col, K=27 pad 32; k = 3*tap + c; 512 blocks ----
    int lb = bi - 1224;                  // 512 = 64 img x 8
    int b = lb >> 3, sub = lb & 7;
    int t = threadIdx.x, lane = t & 63, wv = t >> 6;
    int col = lane & 15, khi = lane >> 4;

    short8v Bf[4];
#pragma unroll
    for (int nb = 0; nb < 4; ++nb) {
        union { short8v v; u16 e[8]; } B;
#pragma unroll
        for (int j = 0; j < 8; ++j) {
            int k = 8 * khi + j;
            B.e[j] = (k < 27) ? f2bf(cw0[k * 64 + nb * 16 + col]) : (u16)0;
        }
        Bf[nb] = B.v;
    }
    float bias[4];
#pragma unroll
    for (int nb = 0; nb < 4; ++nb) bias[nb] = cb0[nb * 16 + col];

    for (int it = 0; it < 2; ++it) {
        int tile = sub * 8 + wv * 2 + it;      // 0..63
        int py = tile >> 1, px0 = (tile & 1) * 16;
        union { short8v v; u16 e[8]; } A;
#pragma unroll
        for (int j = 0; j < 8; ++j) {
            int k = 8 * khi + j;
            float v = 0.f;
            if (k < 27) {
                int tap = k / 3, c = k - 3 * tap;
                int dy = tap / 3, dx = tap - 3 * dy;
                int y = py + dy - 1, x = px0 + col + dx - 1;
                if ((unsigned)y < 32u && (unsigned)x < 32u)
                    v = in[((b * 32 + y) * 32 + x) * 3 + c];
            }
            A.e[j] = f2bf(v);
        }
        f32x4 acc[4];
#pragma unroll
        for (int nb = 0; nb < 4; ++nb) {
            f32x4 ci = {bias[nb], bias[nb], bias[nb], bias[nb]};
            acc[nb] = __builtin_amdgcn_mfma_f32_16x16x32_bf16(A.v, Bf[nb], ci, 0, 0, 0);
        }
#pragma unroll
        for (int r = 0; r < 4; ++r) {
            int px_l = 4 * khi + r;
            u32 lo = (u32)f2bf(fmaxf(acc[0][r], 0.f)) | ((u32)f2bf(fmaxf(acc[1][r], 0.f)) << 16);
            u32 hi = (u32)f2bf(fmaxf(acc[2][r], 0.f)) | ((u32)f2bf(fmaxf(acc[3][r], 0.f)) << 16);
            uint2 pk = {lo, hi};
            *(uint2*)(x0pn + ((size_t)(b * 34 + py + 1) * 34 + px0 + px_l + 1) * 64 + 4 * col) = pk;
        }
    }
}

// ---------------- Layer 1: MFMA, j-contiguous N-tiles, 512 blocks ------------
__global__ __launch_bounds__(256) void l1_mfma(const u16* __restrict__ x0pn,
    const u16* __restrict__ w1q2, const float* __restrict__ cb1, u16* __restrict__ x1pn) {
    __shared__ __align__(16) unsigned char x0s[26112];   // 6 rows x 34 x 64ch bf16
    int bi = blockIdx.x;                 // 512; XCD-swizzled
    int xcd = bi & 7, slot = bi >> 3;
    int b = xcd * 8 + (slot >> 3), rq = slot & 7;
    int t = threadIdx.x, lane = t & 63;
    int g = t >> 6;                      // wave = channel group

    {   // stage rows 4rq..4rq+5 (padded coords), swizzled
        const u16* src = x0pn + (size_t)(b * 1156 + rq * 136) * 64;
        for (int c = t; c < 1632; c += 256) {
            uint4 v = *(const uint4*)(src + c * 8);
            int p = c >> 3;
            int dst = (c * 16) ^ ((p & 7) << 4);
            *(uint4*)(x0s + dst) = v;
        }
    }
    __syncthreads();

    int col = lane & 15, khi = lane >> 4;

    for (int jb = 0; jb < 2; ++jb) {
        short8v wf[9][2];
#pragma unroll
        for (int tap = 0; tap < 9; ++tap)
#pragma unroll
            for (int h = 0; h < 2; ++h)
                wf[tap][h] = *(const short8v*)(w1q2 + (size_t)((((g * 2 + jb) * 9 + tap) * 2 + h) * 64 + lane) * 8);

        float bv = cb1[64 * jb + 4 * col + g];

        for (int mt = 0; mt < 8; ++mt) {
            int row_l = mt >> 1, cbase = (mt & 1) * 16;
            f32x4 acc = {bv, bv, bv, bv};
            int pbase = row_l * 34 + cbase + col;
#pragma unroll
            for (int tap = 0; tap < 9; ++tap) {
                const int dy = tap / 3, dx = tap % 3;
                int p = pbase + dy * 34 + dx;
                int sw = (p & 7) << 4;
                int base = p * 128;
#pragma unroll
                for (int h = 0; h < 2; ++h) {
                    short8v A = *(const short8v*)(x0s + base + ((64 * h + 16 * khi) ^ sw));
                    acc = __builtin_amdgcn_mfma_f32_16x16x32_bf16(A, wf[tap][h], acc, 0, 0, 0);
                }
            }
            int prow = rq * 4 + row_l + 1;
            u16* ob = x1pn + ((size_t)(b * 34 + prow) * 34) * 128 + 32 * g + 16 * jb + col;
#pragma unroll
            for (int r = 0; r < 4; ++r) {
                int pcol = cbase + 4 * khi + r + 1;
                ob[pcol * 128] = f2bf(fmaxf(acc[r], 0.f));
            }
        }
    }
}

// ---------------- Layer 2: MFMA, LDS strips; x2b [kb][b][k'] -----------------
__global__ __launch_bounds__(256) void l2_mfma(const u16* __restrict__ x1pn,
    const u16* __restrict__ w2p, const float* __restrict__ cb2, u16* __restrict__ x2b) {
    __shared__ __align__(16) u16 x1s[6 * 34 * 32];   // 13,056 B
    int bi = blockIdx.x;                 // 2048; XCD-swizzled
    int xcd = bi & 7, slot = bi >> 3;
    int b = xcd * 8 + (slot >> 5);
    int rem = slot & 31;
    int rq = rem >> 2, g = rem & 3;
    int t = threadIdx.x, lane = t & 63, wvi = t >> 6;
    int col = lane & 15, khi = lane >> 4;

    {
        const u16* src = x1pn + (size_t)(b * 34 + rq * 4) * (34 * 128) + g * 32;
        for (int c = t; c < 816; c += 256) {
            int row = c / 136, e = c - row * 136;
            int px = e >> 2, part = e & 3;
            uint4 v = *(const uint4*)(src + (size_t)row * (34 * 128) + px * 128 + part * 8);
            *(uint4*)(x1s + (row * 34 + px) * 32 + part * 8) = v;
        }
    }
    __syncthreads();

    short8v wf[9][2];
#pragma unroll
    for (int tap = 0; tap < 9; ++tap)
#pragma unroll
        for (int nt = 0; nt < 2; ++nt)
            wf[tap][nt] = *(const short8v*)(w2p + (((g * 9 + tap) * 2 + nt) * 64 + lane) * 8);

    float bv0 = cb2[g + 4 * col];
    float bv1 = cb2[g + 4 * (16 + col)];

    int y = rq * 4 + wvi;
    f32x4 acc[2][2];
    acc[0][0] = (f32x4){bv0, bv0, bv0, bv0}; acc[0][1] = (f32x4){bv1, bv1, bv1, bv1};
    acc[1][0] = acc[0][0];                   acc[1][1] = acc[0][1];
#pragma unroll
    for (int tap = 0; tap < 9; ++tap) {
        const int dy = tap / 3, dx = tap % 3;
#pragma unroll
        for (int ms = 0; ms < 2; ++ms) {
            int px = (wvi + dy) * 34 + ms * 16 + col + dx;
            short8v a = *(const short8v*)(x1s + px * 32 + khi * 8);
            acc[ms][0] = __builtin_amdgcn_mfma_f32_16x16x32_bf16(a, wf[tap][0], acc[ms][0], 0, 0, 0);
            acc[ms][1] = __builtin_amdgcn_mfma_f32_16x16x32_bf16(a, wf[tap][1], acc[ms][1], 0, 0, 0);
        }
    }
    // store: x2b[kb][b][k'], kb = (g*2+nt)*64 + y*2+ms, k' = (4khi+r)*16 + col
#pragma unroll
    for (int ms = 0; ms < 2; ++ms)
#pragma unroll
        for (int nt = 0; nt < 2; ++nt) {
            size_t kbase = ((size_t)((g * 2 + nt) * 64 + y * 2 + ms) * 64 + b) * 256;
#pragma unroll
            for (int r = 0; r < 4; ++r) {
                x2b[kbase + (4 * khi + r) * 16 + col] = f2bf(fmaxf(acc[ms][nt][r], 0.f));
            }
        }
}

// ---------------- Dense 1 MFMA: contiguous A-panel per block -----------------
#define D1_NB 512
__global__ __launch_bounds__(256) void d1_mfma(const u16* __restrict__ x2b,
                                               const float* __restrict__ dw1,
                                               float* __restrict__ partial) {
    int kb = blockIdx.x;                 // K-chunk of 256
    int t = threadIdx.x, lane = t & 63, w = t >> 6;
    int col = lane & 15, khi = lane >> 4;
    int n = 16 * w + col;                // output column (50 valid of 64)
    f32x4 acc[4];
#pragma unroll
    for (int m = 0; m < 4; ++m) acc[m] = (f32x4){0.f, 0.f, 0.f, 0.f};

#pragma unroll 2
    for (int ks = 0; ks < 8; ++ks) {
        int kbase = kb * 256 + ks * 32 + 8 * khi;
        int c0 = kbase & 15;
        int q = kbase >> 4;
        int g = q >> 11, nt = (q >> 10) & 1, pix = q & 1023;
        union { short8v v; u16 e[8]; } Bf;
        if (n < 50) {
            const float* wp = dw1 + (size_t)(pix * 128 + g + 64 * nt + 4 * c0) * 50 + n;
#pragma unroll
            for (int j = 0; j < 8; ++j) Bf.e[j] = f2bf(wp[j * 200]);
        } else {
            Bf.v = (short8v)0;
        }
#pragma unroll
        for (int m = 0; m < 4; ++m) {
            short8v A = *(const short8v*)(x2b + ((size_t)kb * 64 + m * 16 + col) * 256
                                          + ks * 32 + 8 * khi);
            acc[m] = __builtin_amdgcn_mfma_f32_16x16x32_bf16(A, Bf.v, acc[m], 0, 0, 0);
        }
    }
#pragma unroll
    for (int m = 0; m < 4; ++m)
#pragma unroll
        for (int r = 0; r < 4; ++r) {
            int brow = m * 16 + khi * 4 + r;
            partial[((size_t)brow * D1_NB + kb) * 64 + n] = acc[m][r];
        }
}

// ---------------- Fused reduce + dense2 + softmax: 64 blocks x 1024 ----------
__global__ __launch_bounds__(1024) void rd2_kernel(const float* __restrict__ partial,
    const float* __restrict__ db1, const float* __restrict__ dw2,
    const float* __restrict__ db2, float* __restrict__ out) {
    __shared__ float sm[16][64];
    __shared__ float hs[64];
    __shared__ float as[10];
    int b = blockIdx.x;                  // batch row
    int t = threadIdx.x;
    int j = t & 63, pp = t >> 6;         // pp 0..15
    const float* pb = partial + ((size_t)b * D1_NB + pp * 32) * 64 + j;
    float s0 = 0.f, s1 = 0.f, s2 = 0.f, s3 = 0.f;
    for (int cb = 0; cb < 32; cb += 4) {
        s0 += pb[(cb + 0) * 64];
        s1 += pb[(cb + 1) * 64];
        s2 += pb[(cb + 2) * 64];
        s3 += pb[(cb + 3) * 64];
    }
    sm[pp][j] = (s0 + s1) + (s2 + s3);
    __syncthreads();
    if (pp == 0) {
        float h = 0.f;
#pragma unroll
        for (int q = 0; q < 16; ++q) h += sm[q][j];
        hs[j] = (j < 50) ? fmaxf(h + db1[j], 0.f) : 0.f;
    }
    __syncthreads();
    if (t < 10) {
        float a = db2[t];
        for (int i = 0; i < 50; ++i) a += hs[i] * dw2[i * 10 + t];
        as[t] = a;
    }
    __syncthreads();
    if (t == 0) {
        float mx = as[0];
#pragma unroll
        for (int q = 1; q < 10; ++q) mx = fmaxf(mx, as[q]);
        float e[10], s = 0.f;
#pragma unroll
        for (int q = 0; q < 10; ++q) { e[q] = expf(as[q] - mx); s += e[q]; }
        float inv = 1.f / s;
#pragma unroll
        for (int q = 0; q < 10; ++q) out[b * 10 + q] = e[q] * inv;
    }
}

// -----------------------------------------------------------------------------
extern "C" void kernel_launch(void* const* d_in, const int* in_sizes, int n_in,
                              void* d_out, int out_size, void* d_ws, size_t ws_size,
                              hipStream_t stream) {
    const float* inputs = (const float*)d_in[0];
    const float* cw0 = (const float*)d_in[1];
    const float* cb0 = (const float*)d_in[2];
    const float* cw1 = (const float*)d_in[3];
    const float* cb1 = (const float*)d_in[4];
    const float* cw2 = (const float*)d_in[5];
    const float* cb2 = (const float*)d_in[6];
    const float* dw1 = (const float*)d_in[7];
    const float* db1 = (const float*)d_in[8];
    const float* dw2 = (const float*)d_in[9];
    const float* db2 = (const float*)d_in[10];
    float* out = (float*)d_out;

    float* ws = (float*)d_ws;
    u16* x1pn = (u16*)ws;
    u16* x0pn = (u16*)(ws + X0PN_OFF);
    u16* x2b  = (u16*)(ws + X2B_OFF);
    float* partial = ws;                  // over dead x1pn (8.4 MB < 18.9 MB)
    u16* w1q2 = (u16*)(ws + W1Q_OFF);
    u16* w2p  = (u16*)(ws + W2P_OFF);

    prep_l0<<<1736, 256, 0, stream>>>(cw1, cw2, inputs, cw0, cb0, x0pn, x1pn, w1q2, w2p);
    l1_mfma<<<512, 256, 0, stream>>>(x0pn, w1q2, cb1, x1pn);
    l2_mfma<<<2048, 256, 0, stream>>>(x1pn, w2p, cb2, x2b);
    d1_mfma<<<D1_NB, 256, 0, stream>>>(x2b, dw1, partial);
    rd2_kernel<<<64, 1024, 0, stream>>>(partial, db1, dw2, db2, out);
}

// Round 13
// 62.505 us; speedup vs baseline: 1.2129x; 1.2129x over previous
//
#include <hip/hip_runtime.h>
#include <math.h>

typedef unsigned short u16;
typedef unsigned int u32;
typedef __attribute__((ext_vector_type(8))) short short8v;    // 8 bf16 (4 VGPR)
typedef __attribute__((ext_vector_type(4))) float f32x4;

// ---------------------------------------------------------------------------
// ws layout (f32 units):
//   x1pn [b][34][34][128] bf16 @ 0          (4,734,976 f32)
//   x0pn [b][34][34][64]  bf16 @ 4,734,976  (2,367,488 f32)
//   x2b  [kb=512][b=64][k'=256] bf16 @ 7,102,464  (4,194,304 f32)
//   partial [64brow][512kb][64n] f32 @ 0 (over dead x1pn, 2,097,152)
//   w1q bf16 @ 11,300,000 (36,864 u16), w2p bf16 @ 11,330,000 (36,864 u16)
// ---------------------------------------------------------------------------
#define X0PN_OFF 4734976
#define X2B_OFF  7102464
#define W1Q_OFF  11300000
#define W2P_OFF  11330000

__device__ __forceinline__ u16 f2bf(float f) {
    union { float f; u32 i; } c; c.f = f;
    u32 r = c.i + 0x7fffu + ((c.i >> 16) & 1u);   // RNE
    return (u16)(r >> 16);
}
__device__ __forceinline__ int Sf(int i0, int m) {
    return (i0 >= 3) ? (i0 - 3 + m) : ((m <= i0) ? m : (12 + m));
}

// ---------------- prep (borders + weight packs) fused with l0 MFMA -----------
__global__ __launch_bounds__(256) void prep_l0(const float* __restrict__ cw1,
    const float* __restrict__ cw2, const float* __restrict__ in,
    const float* __restrict__ cw0, const float* __restrict__ cb0,
    u16* __restrict__ x0pn, u16* __restrict__ x1pn,
    u16* __restrict__ w1q, u16* __restrict__ w2p) {
    int bi = blockIdx.x;
    if (bi < 1080) {
        int t = bi * 256 + threadIdx.x;           // 276,480 total
        if (t < 202752) {
            uint4 z = {0u, 0u, 0u, 0u};
            int cell, v; u16* base; int nch;
            if (t < 67584) { v = t & 7; cell = t >> 3; base = x0pn; nch = 64; }
            else { int u = t - 67584; v = u & 15; cell = u >> 4; base = x1pn; nch = 128; }
            int b = cell / 132, ci = cell - b * 132;
            int y, x;
            if (ci < 34)       { y = 0;       x = ci; }
            else if (ci < 68)  { y = 33;      x = ci - 34; }
            else if (ci < 100) { y = ci - 67; x = 0; }
            else               { y = ci - 99; x = 33; }
            *(uint4*)(base + ((b * 34 + y) * 34 + x) * nch + v * 8) = z;
            return;
        }
        int u0 = t - 202752;                      // 73,728 weight elements
        if (u0 < 36864) {
            int j = u0 & 7, lane = (u0 >> 3) & 63;
            int tp = u0 >> 9;
            int tap = tp % 9, pr = tp / 9;
            int n = lane & 15;
            int k = 8 * (lane >> 4) + j;
            float v = 0.f;
            if (n < 8) {
                if (k < 16) {
                    int f = 4 * (k & 3) + (k >> 2);
                    v = cw1[(tap * 16 + f) * 128 + 2 * pr + 16 * n];
                }
            } else {
                if (k >= 16) {
                    int k2 = k - 16;
                    int f = 4 * (k2 & 3) + (k2 >> 2);
                    v = cw1[(tap * 16 + f) * 128 + 2 * pr + 1 + 16 * (n - 8)];
                }
            }
            w1q[u0] = f2bf(v);
        } else {
            int u = u0 - 36864;
            int j = u & 7, lane = (u >> 3) & 63;
            int nt = (u >> 9) & 1;
            int gt = u >> 10, tap = gt % 9, g = gt / 9;
            int k = 8 * (lane >> 4) + j;
            int f = 4 * (k >> 2) + (k & 3);
            int n = g + 4 * (nt * 16 + (lane & 15));
            w2p[u] = f2bf(cw2[(tap * 32 + f) * 128 + n]);
        }
        return;
    }
    // ---- l0 path: MFMA im2col, K=27 pad 32; k = 3*tap + c; 512 blocks ----
    int lb = bi - 1080;                  // 512 = 64 img x 8
    int b = lb >> 3, sub = lb & 7;
    int t = threadIdx.x, lane = t & 63, wv = t >> 6;
    int col = lane & 15, khi = lane >> 4;

    short8v Bf[4];
#pragma unroll
    for (int nb = 0; nb < 4; ++nb) {
        union { short8v v; u16 e[8]; } B;
#pragma unroll
        for (int j = 0; j < 8; ++j) {
            int k = 8 * khi + j;
            B.e[j] = (k < 27) ? f2bf(cw0[k * 64 + nb * 16 + col]) : (u16)0;
        }
        Bf[nb] = B.v;
    }
    float bias[4];
#pragma unroll
    for (int nb = 0; nb < 4; ++nb) bias[nb] = cb0[nb * 16 + col];

    for (int it = 0; it < 2; ++it) {
        int tile = sub * 8 + wv * 2 + it;      // 0..63
        int py = tile >> 1, px0 = (tile & 1) * 16;
        union { short8v v; u16 e[8]; } A;
#pragma unroll
        for (int j = 0; j < 8; ++j) {
            int k = 8 * khi + j;
            float v = 0.f;
            if (k < 27) {
                int tap = k / 3, c = k - 3 * tap;
                int dy = tap / 3, dx = tap - 3 * dy;
                int y = py + dy - 1, x = px0 + col + dx - 1;
                if ((unsigned)y < 32u && (unsigned)x < 32u)
                    v = in[((b * 32 + y) * 32 + x) * 3 + c];
            }
            A.e[j] = f2bf(v);
        }
        f32x4 acc[4];
#pragma unroll
        for (int nb = 0; nb < 4; ++nb) {
            f32x4 ci = {bias[nb], bias[nb], bias[nb], bias[nb]};
            acc[nb] = __builtin_amdgcn_mfma_f32_16x16x32_bf16(A.v, Bf[nb], ci, 0, 0, 0);
        }
#pragma unroll
        for (int r = 0; r < 4; ++r) {
            int px_l = 4 * khi + r;
            u32 lo = (u32)f2bf(fmaxf(acc[0][r], 0.f)) | ((u32)f2bf(fmaxf(acc[1][r], 0.f)) << 16);
            u32 hi = (u32)f2bf(fmaxf(acc[2][r], 0.f)) | ((u32)f2bf(fmaxf(acc[3][r], 0.f)) << 16);
            uint2 pk = {lo, hi};
            *(uint2*)(x0pn + ((size_t)(b * 34 + py + 1) * 34 + px0 + px_l + 1) * 64 + 4 * col) = pk;
        }
    }
}

// ---------------- Layer 1: MFMA, i0-paired (R11 proven), 1024 blocks ---------
__global__ __launch_bounds__(256) void l1_mfma(const u16* __restrict__ x0pn,
    const u16* __restrict__ w1q, const float* __restrict__ cb1, u16* __restrict__ x1pn) {
    __shared__ __align__(16) unsigned char x0s[26112];   // 6 rows x 34 x 64ch bf16
    int bi = blockIdx.x;                 // 1024; XCD-swizzled
    int xcd = bi & 7, slot = bi >> 3;    // 128 slots per xcd
    int b = xcd * 8 + (slot >> 4);
    int rem = slot & 15;
    int rq = rem >> 1, pp = rem & 1;
    int t = threadIdx.x, lane = t & 63, wv = t >> 6;

    {
        const u16* src = x0pn + (size_t)(b * 1156 + rq * 136) * 64;
        for (int c = t; c < 1632; c += 256) {
            uint4 v = *(const uint4*)(src + c * 8);
            int p = c >> 3;
            int dst = (c * 16) ^ ((p & 7) << 4);
            *(uint4*)(x0s + dst) = v;
        }
    }
    __syncthreads();

    int col = lane & 15, khi = lane >> 4;

    int pr = pp * 4 + wv;                // i0-pair 0..7
    int i0a = 2 * pr, i0b = 2 * pr + 1;
    int i0g = (khi >= 2) ? i0b : i0a;
    int mb = 2 * (khi & 1);
    int o0 = 8 * Sf(i0g, mb), o1 = 8 * Sf(i0g, mb + 1);

    short8v wf[9];
#pragma unroll
    for (int tap = 0; tap < 9; ++tap)
        wf[tap] = *(const short8v*)(w1q + ((pr * 9 + tap) * 64 + lane) * 8);

    int node = (col < 8) ? (i0a + 16 * col) : (i0b + 16 * (col - 8));
    float bv = cb1[node];
    int cperm = 32 * (node & 3) + (node >> 2);

    for (int mt = 0; mt < 8; ++mt) {
        int row_l = mt >> 1, cbase = (mt & 1) * 16;
        f32x4 acc = {bv, bv, bv, bv};
        int pbase = row_l * 34 + cbase + col;
#pragma unroll
        for (int tap = 0; tap < 9; ++tap) {
            const int dy = tap / 3, dx = tap % 3;
            int p = pbase + dy * 34 + dx;
            int sw = (p & 7) << 4;
            int base = p * 128;
            union { short8v v; uint2 h[2]; } A;
            A.h[0] = *(const uint2*)(x0s + base + (o0 ^ sw));
            A.h[1] = *(const uint2*)(x0s + base + (o1 ^ sw));
            acc = __builtin_amdgcn_mfma_f32_16x16x32_bf16(A.v, wf[tap], acc, 0, 0, 0);
        }
        int prow = rq * 4 + row_l + 1;
        u16* ob = x1pn + ((size_t)(b * 34 + prow) * 34) * 128 + cperm;
#pragma unroll
        for (int r = 0; r < 4; ++r) {
            int pcol = cbase + khi * 4 + r + 1;
            ob[pcol * 128] = f2bf(fmaxf(acc[r], 0.f));
        }
    }
}

// ---------------- Layer 2: MFMA, LDS strips; x2b [kb][b][k'] -----------------
__global__ __launch_bounds__(256) void l2_mfma(const u16* __restrict__ x1pn,
    const u16* __restrict__ w2p, const float* __restrict__ cb2, u16* __restrict__ x2b) {
    __shared__ __align__(16) u16 x1s[6 * 34 * 32];   // 13,056 B
    int bi = blockIdx.x;                 // 2048; XCD-swizzled
    int xcd = bi & 7, slot = bi >> 3;
    int b = xcd * 8 + (slot >> 5);
    int rem = slot & 31;
    int rq = rem >> 2, g = rem & 3;
    int t = threadIdx.x, lane = t & 63, wvi = t >> 6;
    int col = lane & 15, khi = lane >> 4;

    {
        const u16* src = x1pn + (size_t)(b * 34 + rq * 4) * (34 * 128) + g * 32;
        for (int c = t; c < 816; c += 256) {
            int row = c / 136, e = c - row * 136;
            int px = e >> 2, part = e & 3;
            uint4 v = *(const uint4*)(src + (size_t)row * (34 * 128) + px * 128 + part * 8);
            *(uint4*)(x1s + (row * 34 + px) * 32 + part * 8) = v;
        }
    }
    __syncthreads();

    short8v wf[9][2];
#pragma unroll
    for (int tap = 0; tap < 9; ++tap)
#pragma unroll
        for (int nt = 0; nt < 2; ++nt)
            wf[tap][nt] = *(const short8v*)(w2p + (((g * 9 + tap) * 2 + nt) * 64 + lane) * 8);

    float bv0 = cb2[g + 4 * col];
    float bv1 = cb2[g + 4 * (16 + col)];

    int y = rq * 4 + wvi;
    f32x4 acc[2][2];
    acc[0][0] = (f32x4){bv0, bv0, bv0, bv0}; acc[0][1] = (f32x4){bv1, bv1, bv1, bv1};
    acc[1][0] = acc[0][0];                   acc[1][1] = acc[0][1];
#pragma unroll
    for (int tap = 0; tap < 9; ++tap) {
        const int dy = tap / 3, dx = tap % 3;
#pragma unroll
        for (int ms = 0; ms < 2; ++ms) {
            int px = (wvi + dy) * 34 + ms * 16 + col + dx;
            short8v a = *(const short8v*)(x1s + px * 32 + khi * 8);
            acc[ms][0] = __builtin_amdgcn_mfma_f32_16x16x32_bf16(a, wf[tap][0], acc[ms][0], 0, 0, 0);
            acc[ms][1] = __builtin_amdgcn_mfma_f32_16x16x32_bf16(a, wf[tap][1], acc[ms][1], 0, 0, 0);
        }
    }
    // store: x2b[kb][b][k'], kb = (g*2+nt)*64 + y*2+ms, k' = (4khi+r)*16 + col
#pragma unroll
    for (int ms = 0; ms < 2; ++ms)
#pragma unroll
        for (int nt = 0; nt < 2; ++nt) {
            size_t kbase = ((size_t)((g * 2 + nt) * 64 + y * 2 + ms) * 64 + b) * 256;
#pragma unroll
            for (int r = 0; r < 4; ++r) {
                x2b[kbase + (4 * khi + r) * 16 + col] = f2bf(fmaxf(acc[ms][nt][r], 0.f));
            }
        }
}

// ---------------- Dense 1 MFMA: contiguous A-panel per block -----------------
#define D1_NB 512
__global__ __launch_bounds__(256) void d1_mfma(const u16* __restrict__ x2b,
                                               const float* __restrict__ dw1,
                                               float* __restrict__ partial) {
    int kb = blockIdx.x;                 // K-chunk of 256
    int t = threadIdx.x, lane = t & 63, w = t >> 6;
    int col = lane & 15, khi = lane >> 4;
    int n = 16 * w + col;                // output column (50 valid of 64)
    f32x4 acc[4];
#pragma unroll
    for (int m = 0; m < 4; ++m) acc[m] = (f32x4){0.f, 0.f, 0.f, 0.f};

#pragma unroll 2
    for (int ks = 0; ks < 8; ++ks) {
        int kbase = kb * 256 + ks * 32 + 8 * khi;
        int c0 = kbase & 15;
        int q = kbase >> 4;
        int g = q >> 11, nt = (q >> 10) & 1, pix = q & 1023;
        union { short8v v; u16 e[8]; } Bf;
        if (n < 50) {
            const float* wp = dw1 + (size_t)(pix * 128 + g + 64 * nt + 4 * c0) * 50 + n;
#pragma unroll
            for (int j = 0; j < 8; ++j) Bf.e[j] = f2bf(wp[j * 200]);
        } else {
            Bf.v = (short8v)0;
        }
#pragma unroll
        for (int m = 0; m < 4; ++m) {
            short8v A = *(const short8v*)(x2b + ((size_t)kb * 64 + m * 16 + col) * 256
                                          + ks * 32 + 8 * khi);
            acc[m] = __builtin_amdgcn_mfma_f32_16x16x32_bf16(A, Bf.v, acc[m], 0, 0, 0);
        }
    }
#pragma unroll
    for (int m = 0; m < 4; ++m)
#pragma unroll
        for (int r = 0; r < 4; ++r) {
            int brow = m * 16 + khi * 4 + r;
            partial[((size_t)brow * D1_NB + kb) * 64 + n] = acc[m][r];
        }
}

// ---------------- Fused reduce + dense2 + softmax: 64 blocks x 1024 ----------
__global__ __launch_bounds__(1024) void rd2_kernel(const float* __restrict__ partial,
    const float* __restrict__ db1, const float* __restrict__ dw2,
    const float* __restrict__ db2, float* __restrict__ out) {
    __shared__ float sm[16][64];
    __shared__ float hs[64];
    __shared__ float as[10];
    int b = blockIdx.x;                  // batch row
    int t = threadIdx.x;
    int j = t & 63, pp = t >> 6;         // pp 0..15
    const float* pb = partial + ((size_t)b * D1_NB + pp * 32) * 64 + j;
    float s0 = 0.f, s1 = 0.f, s2 = 0.f, s3 = 0.f;
    for (int cb = 0; cb < 32; cb += 4) {
        s0 += pb[(cb + 0) * 64];
        s1 += pb[(cb + 1) * 64];
        s2 += pb[(cb + 2) * 64];
        s3 += pb[(cb + 3) * 64];
    }
    sm[pp][j] = (s0 + s1) + (s2 + s3);
    __syncthreads();
    if (pp == 0) {
        float h = 0.f;
#pragma unroll
        for (int q = 0; q < 16; ++q) h += sm[q][j];
        hs[j] = (j < 50) ? fmaxf(h + db1[j], 0.f) : 0.f;
    }
    __syncthreads();
    if (t < 10) {
        float a = db2[t];
        for (int i = 0; i < 50; ++i) a += hs[i] * dw2[i * 10 + t];
        as[t] = a;
    }
    __syncthreads();
    if (t == 0) {
        float mx = as[0];
#pragma unroll
        for (int q = 1; q < 10; ++q) mx = fmaxf(mx, as[q]);
        float e[10], s = 0.f;
#pragma unroll
        for (int q = 0; q < 10; ++q) { e[q] = expf(as[q] - mx); s += e[q]; }
        float inv = 1.f / s;
#pragma unroll
        for (int q = 0; q < 10; ++q) out[b * 10 + q] = e[q] * inv;
    }
}

// -----------------------------------------------------------------------------
extern "C" void kernel_launch(void* const* d_in, const int* in_sizes, int n_in,
                              void* d_out, int out_size, void* d_ws, size_t ws_size,
                              hipStream_t stream) {
    const float* inputs = (const float*)d_in[0];
    const float* cw0 = (const float*)d_in[1];
    const float* cb0 = (const float*)d_in[2];
    const float* cw1 = (const float*)d_in[3];
    const float* cb1 = (const float*)d_in[4];
    const float* cw2 = (const float*)d_in[5];
    const float* cb2 = (const float*)d_in[6];
    const float* dw1 = (const float*)d_in[7];
    const float* db1 = (const float*)d_in[8];
    const float* dw2 = (const float*)d_in[9];
    const float* db2 = (const float*)d_in[10];
    float* out = (float*)d_out;

    float* ws = (float*)d_ws;
    u16* x1pn = (u16*)ws;
    u16* x0pn = (u16*)(ws + X0PN_OFF);
    u16* x2b  = (u16*)(ws + X2B_OFF);
    float* partial = ws;                  // over dead x1pn (8.4 MB < 18.9 MB)
    u16* w1q  = (u16*)(ws + W1Q_OFF);
    u16* w2p  = (u16*)(ws + W2P_OFF);

    prep_l0<<<1592, 256, 0, stream>>>(cw1, cw2, inputs, cw0, cb0, x0pn, x1pn, w1q, w2p);
    l1_mfma<<<1024, 256, 0, stream>>>(x0pn, w1q, cb1, x1pn);
    l2_mfma<<<2048, 256, 0, stream>>>(x1pn, w2p, cb2, x2b);
    d1_mfma<<<D1_NB, 256, 0, stream>>>(x2b, dw1, partial);
    rd2_kernel<<<64, 1024, 0, stream>>>(partial, db1, dw2, db2, out);
}